// Round 3
// baseline (74.342 us; speedup 1.0000x reference)
//
#include <hip/hip_runtime.h>

typedef unsigned short u16;
typedef unsigned int u32;
typedef __attribute__((ext_vector_type(8))) short bfx8;
typedef __attribute__((ext_vector_type(4))) float fx4;
typedef __attribute__((ext_vector_type(4))) u32 ux4;
typedef __attribute__((ext_vector_type(2))) u32 ux2;

__device__ inline u32 f2bf(float v) {
  u32 u = __builtin_bit_cast(u32, v);
  u = (u + 0x7fffu + ((u >> 16) & 1u)) >> 16; // RNE
  return u;
}
__device__ inline float bflo(u32 v) { return __builtin_bit_cast(float, v << 16); }
__device__ inline float bfhi(u32 v) { return __builtin_bit_cast(float, v & 0xffff0000u); }

// ---------------- main MFMA kernel ----------------
// Grid: 256 blocks = 16 b * 16 ich (2 i each). Block: 512 thr = 8 waves.
// Wave w: iLoc = w>>2, h-quarter wq = w&3 -> [64 f][64 h] tile, 8 ksteps.
// s-enumeration within each 8-wide K-run is REVERSED (s2 = s2_0 + 7 - j), baked
// into the As chunk packing, so the x (B-operand) fragment becomes 8 ASCENDING
// consecutive elements of the rotated row -> one 16B-aligned ds_read_b128 via
// 8 shift-replicas per row.
// Epilogue: cross-wave i-merge through LDS red[wq][f][68], then packed bf16
// partial store (dwordx4, coalesced). Partials: 16 chunks * 16 b * 64f * 256h bf16.
__global__ __launch_bounds__(512, 1) void eq_main(const float* __restrict__ xin,
                                                  const float* __restrict__ kin,
                                                  u16* __restrict__ part) {
  __shared__ u16 As[32768];   // [2 i][64 f][32 chunks] bf16; chunks XOR-swizzled,
                              // byte order inside each 8-elem chunk REVERSED
  __shared__ u16 xraw[512];   // [2 i][256 s] bf16 bits
  __shared__ u16 Xrep[4096];  // [2 i][16 r][8 q][16 t]: Xrep[..][q][t] = row[(t+q)&15]
  __shared__ float red[4 * 64 * 68]; // [wq][f][64h + pad4] cross-wave reduce buf

  const int b = blockIdx.x & 15;
  const int ich = blockIdx.x >> 4;
  const int t = threadIdx.x;

  // ---- stage x (2 rows of 256 fp32 -> bf16) ----
  if (t < 128) {
    int iL = t >> 6, s4 = (t & 63) << 2;
    fx4 v = *(const fx4*)(xin + ((b << 5) + (ich << 1) + iL) * 256 + s4);
    ux2 p;
    p[0] = f2bf(v[0]) | (f2bf(v[1]) << 16);
    p[1] = f2bf(v[2]) | (f2bf(v[3]) << 16);
    *(ux2*)(xraw + iL * 256 + s4) = p;
  }

  // ---- stage kernel slice: 2 i * 64 f * 256 s fp32 -> bf16 LDS ----
  // dest slot = chunk XOR-swizzled; within-chunk element order reversed.
#pragma unroll
  for (int it = 0; it < 8; ++it) {
    int slot = it * 512 + t; // 0..4095
    int iL = slot >> 11;
    int f = (slot >> 5) & 63;
    int c = slot & 31;
    int cs = c ^ (f & 31); // source chunk (un-swizzle)
    const float* src = kin + f * 8192 + ((ich << 1) + iL) * 256 + (cs << 3);
    fx4 v0 = *(const fx4*)src;      // s = base+0..3
    fx4 v1 = *(const fx4*)(src + 4); // s = base+4..7
    ux4 p;                           // reversed: elem j = src[7-j]
    p[0] = f2bf(v1[3]) | (f2bf(v1[2]) << 16);
    p[1] = f2bf(v1[1]) | (f2bf(v1[0]) << 16);
    p[2] = f2bf(v0[3]) | (f2bf(v0[2]) << 16);
    p[3] = f2bf(v0[1]) | (f2bf(v0[0]) << 16);
    *(ux4*)(As + slot * 8) = p;
  }
  __syncthreads();

  // ---- build Xrep shift-replicas from xraw ----
  {
    int triple = t >> 1;             // [0,256): i(1) r(4) q(3)
    int iL = triple >> 7, r = (triple >> 3) & 15, q = triple & 7;
    int th = (t & 1) * 8;
    const u16* xr = xraw + iL * 256 + r * 16;
    u16* xd = Xrep + ((iL * 16 + r) * 8 + q) * 16 + th;
#pragma unroll
    for (int j = 0; j < 8; ++j) xd[j] = xr[(th + j + q) & 15];
  }
  __syncthreads();

  const int lane = t & 63;
  const int w = t >> 6;
  const int iL = w >> 2;
  const int wq = w & 3;
  const int n = lane & 15;    // MFMA col (h2) / A row (f low bits)
  const int quad = lane >> 4; // k-group
  const int s1q = quad >> 1;
  // c0 = start col of the ascending 8-run: (h2 - s2_0 - 7) mod 16
  const int c0 = (n - ((quad & 1) << 3) + 9) & 15;
  const int XB = iL * 2048 + (c0 & 7) * 16 + (c0 & 8); // lane-const elem offset
  const u16* Aw = As + (iL << 14);

  fx4 acc[4][4];
#pragma unroll
  for (int a = 0; a < 4; ++a)
#pragma unroll
    for (int c = 0; c < 4; ++c) acc[a][c] = (fx4){0.f, 0.f, 0.f, 0.f};

#pragma unroll
  for (int kstep = 0; kstep < 8; ++kstep) {
    bfx8 af[4];
#pragma unroll
    for (int ft = 0; ft < 4; ++ft) {
      int f = (ft << 4) + n;
      int ch = ((kstep << 2) + quad) ^ (f & 31);
      af[ft] = *(const bfx8*)(Aw + f * 256 + ch * 8);
    }
    const int s1 = (kstep << 1) + s1q;
    bfx8 bfr[4];
#pragma unroll
    for (int ht = 0; ht < 4; ++ht) {
      int r = ((wq << 2) + ht - s1) & 15; // x row (h1 - s1) mod 16
      bfr[ht] = *(const bfx8*)(Xrep + XB + r * 128); // one 16B-aligned b128
    }
#pragma unroll
    for (int ft = 0; ft < 4; ++ft)
#pragma unroll
      for (int ht = 0; ht < 4; ++ht)
        acc[ft][ht] =
            __builtin_amdgcn_mfma_f32_16x16x32_bf16(af[ft], bfr[ht], acc[ft][ht], 0, 0, 0);
  }

  // ---- epilogue: i-merge via red[wq][f][68], then packed bf16 partial store ----
  if (w >= 4) {
    float* rb = red + wq * 4352;
#pragma unroll
    for (int ft = 0; ft < 4; ++ft)
#pragma unroll
      for (int ht = 0; ht < 4; ++ht)
#pragma unroll
        for (int reg = 0; reg < 4; ++reg)
          rb[((ft << 4) + (quad << 2) + reg) * 68 + (ht << 4) + n] = acc[ft][ht][reg];
  }
  __syncthreads();
  if (w < 4) {
    float* rb = red + wq * 4352;
#pragma unroll
    for (int ft = 0; ft < 4; ++ft)
#pragma unroll
      for (int ht = 0; ht < 4; ++ht)
#pragma unroll
        for (int reg = 0; reg < 4; ++reg) {
          int idx = ((ft << 4) + (quad << 2) + reg) * 68 + (ht << 4) + n;
          rb[idx] += acc[ft][ht][reg];
        }
  }
  __syncthreads();
  // all 512 threads: pack [64 f][256 h] bf16, coalesced dwordx4 stores
  {
    u16* pw = part + (((ich << 4) + b) << 14);
#pragma unroll
    for (int it = 0; it < 4; ++it) {
      int task = it * 512 + t;      // f = task>>5, o (h-octet) = task&31
      int f = task >> 5, o = task & 31;
      const float* rr = red + (o >> 3) * 4352 + f * 68 + (o & 7) * 8;
      fx4 v0 = *(const fx4*)rr;
      fx4 v1 = *(const fx4*)(rr + 4);
      ux4 p;
      p[0] = f2bf(v0[0]) | (f2bf(v0[1]) << 16);
      p[1] = f2bf(v0[2]) | (f2bf(v0[3]) << 16);
      p[2] = f2bf(v1[0]) | (f2bf(v1[1]) << 16);
      p[3] = f2bf(v1[2]) | (f2bf(v1[3]) << 16);
      *(ux4*)(pw + f * 256 + o * 8) = p;
    }
  }
}

// ---------------- split-K reduction (bf16 partials) + bias ----------------
__global__ __launch_bounds__(256) void eq_reduce(const u16* __restrict__ part,
                                                 const float* __restrict__ bias,
                                                 float* __restrict__ out) {
  int o8 = (blockIdx.x * 256 + threadIdx.x) * 8;
  float s[8] = {0.f, 0.f, 0.f, 0.f, 0.f, 0.f, 0.f, 0.f};
#pragma unroll
  for (int c = 0; c < 16; ++c) {
    ux4 v = *(const ux4*)(part + c * 262144 + o8);
#pragma unroll
    for (int d = 0; d < 4; ++d) {
      s[2 * d] += bflo(v[d]);
      s[2 * d + 1] += bfhi(v[d]);
    }
  }
  float bv = bias[(o8 >> 8) & 63];
  fx4 r0 = {s[0] + bv, s[1] + bv, s[2] + bv, s[3] + bv};
  fx4 r1 = {s[4] + bv, s[5] + bv, s[6] + bv, s[7] + bv};
  *(fx4*)(out + o8) = r0;
  *(fx4*)(out + o8 + 4) = r1;
}

extern "C" void kernel_launch(void* const* d_in, const int* in_sizes, int n_in,
                              void* d_out, int out_size, void* d_ws, size_t ws_size,
                              hipStream_t stream) {
  (void)in_sizes; (void)n_in; (void)out_size; (void)ws_size;
  const float* x = (const float*)d_in[0];
  const float* k = (const float*)d_in[1];
  const float* bias = (const float*)d_in[2];
  // d_in[3] (product_table) unused: translation-group indices computed analytically.
  u16* part = (u16*)d_ws; // 16 chunks * 16 b * 64 f * 256 h * 2 B = 8.4 MB
  float* out = (float*)d_out;

  eq_main<<<256, 512, 0, stream>>>(x, k, part);
  eq_reduce<<<128, 256, 0, stream>>>(part, bias, out);
}